// Round 7
// baseline (205.483 us; speedup 1.0000x reference)
//
#include <hip/hip_runtime.h>
#include <math.h>

constexpr int SEQ  = 2048;
constexpr int HID  = 1024;
constexpr int MTOT = 4096;     // B*S
constexpr int BH   = 32;       // B*nh

typedef _Float16 f16;
typedef _Float16 f16x8 __attribute__((ext_vector_type(8)));
typedef float    f32x4 __attribute__((ext_vector_type(4)));

// ---------------------------------------------------------------------------
// convert x fp32 -> fp16, same layout [M][1024]
// ---------------------------------------------------------------------------
__global__ __launch_bounds__(256) void cvt_x(const float* __restrict__ in,
                                             f16* __restrict__ out) {
    const int i = (blockIdx.x * 256 + threadIdx.x) * 4;
    float4 v = *(const float4*)(in + i);
    f16 o[4] = {(f16)v.x, (f16)v.y, (f16)v.z, (f16)v.w};
    *(ushort4*)(out + i) = *(ushort4*)o;
}

// ---------------------------------------------------------------------------
// Fused weight transpose+convert: z=0: Wq-Wk -> WqkT, z=1: Wv -> WvT, z=2: Wo
// ---------------------------------------------------------------------------
__global__ __launch_bounds__(256) void cvt_w_all(const float* __restrict__ Wq,
                                                 const float* __restrict__ Wk,
                                                 const float* __restrict__ Wv,
                                                 const float* __restrict__ Wo,
                                                 f16* __restrict__ WqkT,
                                                 f16* __restrict__ WvT,
                                                 f16* __restrict__ WoT) {
    __shared__ f16 T[64][72];
    const int z = blockIdx.z;
    const float* W  = (z == 0) ? Wq : (z == 1) ? Wv : Wo;
    const float* W2 = Wk;
    f16* WT = (z == 0) ? WqkT : (z == 1) ? WvT : WoT;

    const int k0 = blockIdx.x * 64, n0 = blockIdx.y * 64;
    const int t = threadIdx.x;
    const int r  = t >> 4;
    const int c4 = (t & 15) * 4;
#pragma unroll
    for (int rr = 0; rr < 64; rr += 16) {
        float4 w = *(const float4*)(W + (size_t)(k0 + rr + r) * HID + n0 + c4);
        if (z == 0) {
            float4 w2 = *(const float4*)(W2 + (size_t)(k0 + rr + r) * HID + n0 + c4);
            w.x -= w2.x; w.y -= w2.y; w.z -= w2.z; w.w -= w2.w;
        }
        T[c4 + 0][rr + r] = (f16)w.x;
        T[c4 + 1][rr + r] = (f16)w.y;
        T[c4 + 2][rr + r] = (f16)w.z;
        T[c4 + 3][rr + r] = (f16)w.w;
    }
    __syncthreads();
#pragma unroll
    for (int pp = 0; pp < 2; pp++) {
        const int nr = pp * 32 + (t >> 3);
        const int kc = (t & 7) * 8;
        *(uint4*)(WT + (size_t)(n0 + nr) * HID + k0 + kc) = *(uint4*)(&T[nr][kc]);
    }
}

// ---------------------------------------------------------------------------
// Fused projection GEMM (dif + vT): N=2048 virtual (first 1024 -> dif, rest -> vT)
// ---------------------------------------------------------------------------
__global__ __launch_bounds__(256) void proj_gemm(const f16* __restrict__ A,
                                                 const f16* __restrict__ WqkT,
                                                 const f16* __restrict__ WvT,
                                                 const float* __restrict__ bq,
                                                 const float* __restrict__ bk,
                                                 const float* __restrict__ bv,
                                                 f16* __restrict__ dif,
                                                 f16* __restrict__ vT) {
    __shared__ f16 As[128 * 72];
    __shared__ f16 Bs[128 * 72];
    const int t = threadIdx.x;
    const int m0  = blockIdx.x * 128;
    const int n0g = blockIdx.y * 128;
    const bool isv = (n0g >= HID);
    const f16* BT = isv ? WvT : WqkT;
    const int n0 = n0g & (HID - 1);
    const int w = t >> 6, l = t & 63, quad = l >> 4, ln = l & 15;
    const int wm = (w >> 1) * 64, wn = (w & 1) * 64;
    const int srow = t >> 1, shalf = (t & 1) * 32;

    const f16* pa = A  + (size_t)(m0 + srow) * HID + shalf;
    const f16* pb = BT + (size_t)(n0 + srow) * HID + shalf;

    uint4 ar0 = *(const uint4*)(pa),      ar1 = *(const uint4*)(pa + 8);
    uint4 ar2 = *(const uint4*)(pa + 16), ar3 = *(const uint4*)(pa + 24);
    uint4 br0 = *(const uint4*)(pb),      br1 = *(const uint4*)(pb + 8);
    uint4 br2 = *(const uint4*)(pb + 16), br3 = *(const uint4*)(pb + 24);

    f32x4 acc[4][4] = {};

    for (int k0 = 0; k0 < HID; k0 += 64) {
        __syncthreads();
        f16* da = As + srow * 72 + shalf;
        f16* db = Bs + srow * 72 + shalf;
        *(uint4*)(da)      = ar0; *(uint4*)(da + 8)  = ar1;
        *(uint4*)(da + 16) = ar2; *(uint4*)(da + 24) = ar3;
        *(uint4*)(db)      = br0; *(uint4*)(db + 8)  = br1;
        *(uint4*)(db + 16) = br2; *(uint4*)(db + 24) = br3;
        __syncthreads();
        if (k0 + 64 < HID) {
            const f16* qa = pa + k0 + 64;
            const f16* qb = pb + k0 + 64;
            ar0 = *(const uint4*)(qa);      ar1 = *(const uint4*)(qa + 8);
            ar2 = *(const uint4*)(qa + 16); ar3 = *(const uint4*)(qa + 24);
            br0 = *(const uint4*)(qb);      br1 = *(const uint4*)(qb + 8);
            br2 = *(const uint4*)(qb + 16); br3 = *(const uint4*)(qb + 24);
        }
#pragma unroll
        for (int kh = 0; kh < 2; kh++) {
            f16x8 af[4], bf[4];
#pragma unroll
            for (int mt = 0; mt < 4; mt++)
                af[mt] = *(const f16x8*)(As + (wm + mt * 16 + ln) * 72 + kh * 32 + quad * 8);
#pragma unroll
            for (int nt = 0; nt < 4; nt++)
                bf[nt] = *(const f16x8*)(Bs + (wn + nt * 16 + ln) * 72 + kh * 32 + quad * 8);
#pragma unroll
            for (int mt = 0; mt < 4; mt++)
#pragma unroll
                for (int nt = 0; nt < 4; nt++)
                    acc[mt][nt] = __builtin_amdgcn_mfma_f32_16x16x32_f16(
                        af[mt], bf[nt], acc[mt][nt], 0, 0, 0);
        }
    }

#pragma unroll
    for (int mt = 0; mt < 4; mt++) {
#pragma unroll
        for (int nt = 0; nt < 4; nt++) {
            const int nl = n0 + wn + nt * 16 + ln;
            const int m_base = m0 + wm + mt * 16 + quad * 4;
            const int h = nl >> 6, e = nl & 63;
            if (!isv) {
                const float bb = bq[nl] - bk[nl];
#pragma unroll
                for (int r = 0; r < 4; r++) {
                    const int m = m_base + r;
                    const int b = m >> 11, s = m & 2047;
                    dif[((size_t)(b * 16 + h) * SEQ + s) * 64 + e] =
                        (f16)(acc[mt][nt][r] + bb);
                }
            } else {
                const float bb = bv[nl];
                const int b = m_base >> 11, s0 = m_base & 2047;
                f16 o[4];
#pragma unroll
                for (int r = 0; r < 4; r++) o[r] = (f16)(acc[mt][nt][r] + bb);
                *(ushort4*)(&vT[((size_t)(b * 16 + h) * 64 + e) * SEQ + s0]) =
                    *(ushort4*)o;
            }
        }
    }
}

// ---------------------------------------------------------------------------
// Output GEMM: out = (C0+C1+C2) @ WoT^T * 65536 + bo.  128x64 tile, 512 blocks.
// ---------------------------------------------------------------------------
__global__ __launch_bounds__(256) void out_gemm(const f16* __restrict__ C0,
                                                const f16* __restrict__ C1,
                                                const f16* __restrict__ C2,
                                                const f16* __restrict__ WoT,
                                                const float* __restrict__ bo,
                                                float* __restrict__ out) {
    __shared__ f16 As[128 * 72];
    __shared__ f16 Bs[64 * 72];
    const int t = threadIdx.x;
    const int m0 = blockIdx.x * 128, n0 = blockIdx.y * 64;
    const int w = t >> 6, l = t & 63, quad = l >> 4, ln = l & 15;
    const int wm = (w >> 1) * 64, wn = (w & 1) * 32;
    const int arow = t >> 1, ahalf = (t & 1) * 32;
    const int brow = t >> 2, boff = (t & 3) * 16;

    const f16* pa0 = C0  + (size_t)(m0 + arow) * HID + ahalf;
    const f16* pa1 = C1  + (size_t)(m0 + arow) * HID + ahalf;
    const f16* pa2 = C2  + (size_t)(m0 + arow) * HID + ahalf;
    const f16* pb  = WoT + (size_t)(n0 + brow) * HID + boff;

    f16x8 a0 = *(const f16x8*)(pa0)      + *(const f16x8*)(pa1)      + *(const f16x8*)(pa2);
    f16x8 a1 = *(const f16x8*)(pa0 + 8)  + *(const f16x8*)(pa1 + 8)  + *(const f16x8*)(pa2 + 8);
    f16x8 a2 = *(const f16x8*)(pa0 + 16) + *(const f16x8*)(pa1 + 16) + *(const f16x8*)(pa2 + 16);
    f16x8 a3 = *(const f16x8*)(pa0 + 24) + *(const f16x8*)(pa1 + 24) + *(const f16x8*)(pa2 + 24);
    uint4 b0 = *(const uint4*)(pb), b1 = *(const uint4*)(pb + 8);

    f32x4 acc[4][2] = {};

    for (int k0 = 0; k0 < HID; k0 += 64) {
        __syncthreads();
        f16* da = As + arow * 72 + ahalf;
        *(f16x8*)(da)      = a0; *(f16x8*)(da + 8)  = a1;
        *(f16x8*)(da + 16) = a2; *(f16x8*)(da + 24) = a3;
        f16* db = Bs + brow * 72 + boff;
        *(uint4*)(db) = b0; *(uint4*)(db + 8) = b1;
        __syncthreads();
        if (k0 + 64 < HID) {
            const int kn = k0 + 64;
            a0 = *(const f16x8*)(pa0 + kn)      + *(const f16x8*)(pa1 + kn)      + *(const f16x8*)(pa2 + kn);
            a1 = *(const f16x8*)(pa0 + kn + 8)  + *(const f16x8*)(pa1 + kn + 8)  + *(const f16x8*)(pa2 + kn + 8);
            a2 = *(const f16x8*)(pa0 + kn + 16) + *(const f16x8*)(pa1 + kn + 16) + *(const f16x8*)(pa2 + kn + 16);
            a3 = *(const f16x8*)(pa0 + kn + 24) + *(const f16x8*)(pa1 + kn + 24) + *(const f16x8*)(pa2 + kn + 24);
            b0 = *(const uint4*)(pb + kn); b1 = *(const uint4*)(pb + kn + 8);
        }
#pragma unroll
        for (int kh = 0; kh < 2; kh++) {
            f16x8 af[4], bf[2];
#pragma unroll
            for (int mt = 0; mt < 4; mt++)
                af[mt] = *(const f16x8*)(As + (wm + mt * 16 + ln) * 72 + kh * 32 + quad * 8);
#pragma unroll
            for (int nt = 0; nt < 2; nt++)
                bf[nt] = *(const f16x8*)(Bs + (wn + nt * 16 + ln) * 72 + kh * 32 + quad * 8);
#pragma unroll
            for (int mt = 0; mt < 4; mt++)
#pragma unroll
                for (int nt = 0; nt < 2; nt++)
                    acc[mt][nt] = __builtin_amdgcn_mfma_f32_16x16x32_f16(
                        af[mt], bf[nt], acc[mt][nt], 0, 0, 0);
        }
    }

#pragma unroll
    for (int mt = 0; mt < 4; mt++)
#pragma unroll
        for (int nt = 0; nt < 2; nt++) {
            const int n = n0 + wn + nt * 16 + ln;
            const float bb = bo[n];
            const int m_base = m0 + wm + mt * 16 + quad * 4;
#pragma unroll
            for (int r = 0; r < 4; r++)
                out[(size_t)(m_base + r) * HID + n] =
                    acc[mt][nt][r] * 65536.0f + bb;
        }
}

// ---------------------------------------------------------------------------
// fp16 MFMA attention, Q128/wave32 + Q-in-regs + ks-split 3.
// Block (pq, bh, ks): q-tiles (pq, 15-pq) of 128 rows; k-tiles kt = 2*qt+ks,
// step 3. Each wave owns 32 q-rows (2 strips of 16). Partial ctx -> buffer ks.
// LDS 36.9 KB: KV (Ks 64x72 | Vs 64x72; Q staged flat through it) + Ps 128x72.
// ---------------------------------------------------------------------------
__global__ __launch_bounds__(256) void attn_f16(const f16* __restrict__ dif,
                                                const f16* __restrict__ vT,
                                                f16* __restrict__ ctx0,
                                                f16* __restrict__ ctx1,
                                                f16* __restrict__ ctx2) {
    constexpr int LP = 72;
    __shared__ f16 KV[2 * 64 * LP];
    __shared__ f16 Ps[128 * LP];
    f16* Ks = KV;
    f16* Vs = KV + 64 * LP;

    const int pq = blockIdx.x, bh = blockIdx.y, ks = blockIdx.z;
    f16* Cout = (ks == 0) ? ctx0 : (ks == 1) ? ctx1 : ctx2;
    const f16* D  = dif + (size_t)bh * SEQ * 64;
    const f16* VT = vT  + (size_t)bh * 64 * SEQ;
    const int b = bh >> 4, h = bh & 15;
    const int t = threadIdx.x, w = t >> 6, l = t & 63, quad = l >> 4, ln = l & 15;
    const int ve = t >> 2, vc = (t & 3) * 16;

    for (int half = 0; half < 2; half++) {
        const int qt = half ? (15 - pq) : pq;
        const int i0 = qt * 128;
        __syncthreads();   // prior half's LDS reads complete

        // stage Q (128x64, flat pitch 64) through KV, pull frags to regs
#pragma unroll
        for (int c = 0; c < 4; c++) {
            const int o = c * 2048 + t * 8;
            *(uint4*)(&KV[o]) = *(const uint4*)(D + (size_t)i0 * 64 + o);
        }
        __syncthreads();
        f16x8 aq[2][2];
#pragma unroll
        for (int st = 0; st < 2; st++)
#pragma unroll
            for (int kh = 0; kh < 2; kh++)
                aq[st][kh] = *(const f16x8*)(&KV[(w * 32 + st * 16 + ln) * 64
                                                + kh * 32 + quad * 8]);
        __syncthreads();   // everyone has Q frags; KV free for K/V

        f32x4 acc[2][4] = {};
        const int kt0 = qt * 2 + ks;

        uint4 kr0, kr1, vr0, vr1;
        if (kt0 < 32) {
            const int j0 = kt0 * 64;
            kr0 = *(const uint4*)(D + (size_t)j0 * 64 + t * 8);
            kr1 = *(const uint4*)(D + (size_t)j0 * 64 + 2048 + t * 8);
            vr0 = *(const uint4*)(VT + (size_t)ve * SEQ + j0 + vc);
            vr1 = *(const uint4*)(VT + (size_t)ve * SEQ + j0 + vc + 8);
        }

        for (int kt = kt0; kt < 32; kt += 3) {
            const int j0 = kt * 64;
            __syncthreads();   // prior iter K/V frag reads done

            {   // staged regs -> LDS
                const int o0 = t * 8, o1 = 2048 + t * 8;
                *(uint4*)(&Ks[(o0 >> 6) * LP + (o0 & 63)]) = kr0;
                *(uint4*)(&Ks[(o1 >> 6) * LP + (o1 & 63)]) = kr1;
                *(uint4*)(&Vs[ve * LP + vc])     = vr0;
                *(uint4*)(&Vs[ve * LP + vc + 8]) = vr1;
            }
            __syncthreads();

            if (kt + 3 < 32) {
                const int j2 = (kt + 3) * 64;
                kr0 = *(const uint4*)(D + (size_t)j2 * 64 + t * 8);
                kr1 = *(const uint4*)(D + (size_t)j2 * 64 + 2048 + t * 8);
                vr0 = *(const uint4*)(VT + (size_t)ve * SEQ + j2 + vc);
                vr1 = *(const uint4*)(VT + (size_t)ve * SEQ + j2 + vc + 8);
            }

            const int gi0 = i0 + w * 32;          // strip0 global row base
            const bool live0 = (j0 + 63) > gi0;
            const bool live1 = (j0 + 63) > (gi0 + 16);

            // ---- S = Q . K^T ----
            f32x4 s[2][4] = {};
#pragma unroll
            for (int kh = 0; kh < 2; kh++)
#pragma unroll
                for (int nt = 0; nt < 4; nt++) {
                    f16x8 bk = *(const f16x8*)(&Ks[(nt * 16 + ln) * LP + kh * 32 + quad * 8]);
                    if (live0) s[0][nt] = __builtin_amdgcn_mfma_f32_16x16x32_f16(
                                              aq[0][kh], bk, s[0][nt], 0, 0, 0);
                    if (live1) s[1][nt] = __builtin_amdgcn_mfma_f32_16x16x32_f16(
                                              aq[1][kh], bk, s[1][nt], 0, 0, 0);
                }

            // ---- P = mask * exp(-0.5*s - 16*ln2)  (pre-scaled 2^-16) ----
#pragma unroll
            for (int st = 0; st < 2; st++) {
                const bool live = st ? live1 : live0;
                if (!live) continue;               // wave-uniform
                const int gs = gi0 + st * 16;
                const bool nomask = j0 > gs + 15;  // tile fully above diagonal
#pragma unroll
                for (int nt = 0; nt < 4; nt++)
#pragma unroll
                    for (int r = 0; r < 4; r++) {
                        float p = __expf(fmaf(s[st][nt][r], -0.5f, -11.090354888959125f));
                        p = fminf(p, 60000.0f);
                        if (!nomask) {
                            const int gi = gs + quad * 4 + r;
                            const int gj = j0 + nt * 16 + ln;
                            p = (gj > gi) ? p : 0.0f;
                        }
                        Ps[(w * 32 + st * 16 + quad * 4 + r) * LP + nt * 16 + ln] = (f16)p;
                    }
            }
            // no barrier: Ps rows wave-private

            // ---- ctx += P @ V ----
#pragma unroll
            for (int kh = 0; kh < 2; kh++) {
                f16x8 ap0, ap1;
                if (live0) ap0 = *(const f16x8*)(&Ps[(w * 32 + ln) * LP + kh * 32 + quad * 8]);
                if (live1) ap1 = *(const f16x8*)(&Ps[(w * 32 + 16 + ln) * LP + kh * 32 + quad * 8]);
#pragma unroll
                for (int nt = 0; nt < 4; nt++) {
                    f16x8 bv = *(const f16x8*)(&Vs[(nt * 16 + ln) * LP + kh * 32 + quad * 8]);
                    if (live0) acc[0][nt] = __builtin_amdgcn_mfma_f32_16x16x32_f16(
                                                ap0, bv, acc[0][nt], 0, 0, 0);
                    if (live1) acc[1][nt] = __builtin_amdgcn_mfma_f32_16x16x32_f16(
                                                ap1, bv, acc[1][nt], 0, 0, 0);
                }
            }
        }

        // ---- partial ctx (scaled 2^-16), row-major [M][1024] ----
#pragma unroll
        for (int st = 0; st < 2; st++)
#pragma unroll
            for (int nt = 0; nt < 4; nt++)
#pragma unroll
                for (int r = 0; r < 4; r++) {
                    const int iloc = w * 32 + st * 16 + quad * 4 + r;
                    Cout[(size_t)(b * SEQ + i0 + iloc) * HID + h * 64 + nt * 16 + ln] =
                        (f16)acc[st][nt][r];
                }
    }
}

// ---------------------------------------------------------------------------
extern "C" void kernel_launch(void* const* d_in, const int* in_sizes, int n_in,
                              void* d_out, int out_size, void* d_ws, size_t ws_size,
                              hipStream_t stream) {
    const float* x  = (const float*)d_in[0];
    const float* Wq = (const float*)d_in[1];
    const float* bq = (const float*)d_in[2];
    const float* Wk = (const float*)d_in[3];
    const float* bk = (const float*)d_in[4];
    const float* Wv = (const float*)d_in[5];
    const float* bv = (const float*)d_in[6];
    const float* Wo = (const float*)d_in[7];
    const float* bo = (const float*)d_in[8];
    float* out = (float*)d_out;

    char* ws = (char*)d_ws;
    f16* xh   = (f16*)(ws);               // 8 MB  [M][1024]   (dead after proj)
    f16* WqkT = (f16*)(ws + (8 << 20));   // 2 MB  [n][k]
    f16* WvT  = (f16*)(ws + (10 << 20));  // 2 MB
    f16* WoT  = (f16*)(ws + (12 << 20));  // 2 MB
    f16* dif  = (f16*)(ws + (14 << 20));  // 8 MB  [bh][s][64]
    f16* vT   = (f16*)(ws + (22 << 20));  // 8 MB  [bh][e][s]
    f16* ctx0 = (f16*)(ws + (30 << 20));  // 8 MB  partial (x 2^-16)
    f16* ctx1 = (f16*)(ws + (38 << 20));  // 8 MB  partial
    f16* ctx2 = xh;                       // reuse xh region (dead after proj)

    cvt_x<<<MTOT * HID / 1024, 256, 0, stream>>>(x, xh);
    cvt_w_all<<<dim3(16, 16, 3), 256, 0, stream>>>(Wq, Wk, Wv, Wo, WqkT, WvT, WoT);

    proj_gemm<<<dim3(MTOT / 128, 16), 256, 0, stream>>>(xh, WqkT, WvT,
                                                        bq, bk, bv, dif, vT);
    attn_f16<<<dim3(8, BH, 3), 256, 0, stream>>>(dif, vT, ctx0, ctx1, ctx2);
    out_gemm<<<dim3(MTOT / 128, 16), 256, 0, stream>>>(ctx0, ctx1, ctx2, WoT, bo, out);
}

// Round 8
// 188.003 us; speedup vs baseline: 1.0930x; 1.0930x over previous
//
#include <hip/hip_runtime.h>
#include <math.h>

constexpr int SEQ  = 2048;
constexpr int HID  = 1024;
constexpr int MTOT = 4096;     // B*S
constexpr int BH   = 32;       // B*nh

typedef _Float16 f16;
typedef _Float16 f16x8 __attribute__((ext_vector_type(8)));
typedef float    f32x4 __attribute__((ext_vector_type(4)));

// ---------------------------------------------------------------------------
// prep: z=0: Wq-Wk -> WqkT, z=1: Wv -> WvT, z=2: Wo -> WoT  (transpose+f16)
//       z=3: x fp32 -> f16 flat copy
// ---------------------------------------------------------------------------
__global__ __launch_bounds__(256) void prep(const float* __restrict__ x,
                                            const float* __restrict__ Wq,
                                            const float* __restrict__ Wk,
                                            const float* __restrict__ Wv,
                                            const float* __restrict__ Wo,
                                            f16* __restrict__ xh,
                                            f16* __restrict__ WqkT,
                                            f16* __restrict__ WvT,
                                            f16* __restrict__ WoT) {
    __shared__ f16 T[64][72];
    const int z = blockIdx.z;
    const int t = threadIdx.x;

    if (z == 3) {   // x convert: 256 chunks of 16384 elems
        const int chunk = blockIdx.y * 16 + blockIdx.x;
        const float* src = x + (size_t)chunk * 16384;
        f16* dst = xh + (size_t)chunk * 16384;
#pragma unroll
        for (int it = 0; it < 16; it++) {
            const int i = it * 1024 + t * 4;
            float4 v = *(const float4*)(src + i);
            f16 o[4] = {(f16)v.x, (f16)v.y, (f16)v.z, (f16)v.w};
            *(ushort4*)(dst + i) = *(ushort4*)o;
        }
        return;
    }

    const float* W  = (z == 0) ? Wq : (z == 1) ? Wv : Wo;
    f16* WT = (z == 0) ? WqkT : (z == 1) ? WvT : WoT;
    const int k0 = blockIdx.x * 64, n0 = blockIdx.y * 64;
    const int r  = t >> 4;
    const int c4 = (t & 15) * 4;
#pragma unroll
    for (int rr = 0; rr < 64; rr += 16) {
        float4 w = *(const float4*)(W + (size_t)(k0 + rr + r) * HID + n0 + c4);
        if (z == 0) {
            float4 w2 = *(const float4*)(Wk + (size_t)(k0 + rr + r) * HID + n0 + c4);
            w.x -= w2.x; w.y -= w2.y; w.z -= w2.z; w.w -= w2.w;
        }
        T[c4 + 0][rr + r] = (f16)w.x;
        T[c4 + 1][rr + r] = (f16)w.y;
        T[c4 + 2][rr + r] = (f16)w.z;
        T[c4 + 3][rr + r] = (f16)w.w;
    }
    __syncthreads();
#pragma unroll
    for (int pp = 0; pp < 2; pp++) {
        const int nr = pp * 32 + (t >> 3);
        const int kc = (t & 7) * 8;
        *(uint4*)(WT + (size_t)(n0 + nr) * HID + k0 + kc) = *(uint4*)(&T[nr][kc]);
    }
}

// ---------------------------------------------------------------------------
// Fused projection GEMM (dif + vT), double-buffered LDS (1 barrier/iter).
// N=2048 virtual: first 1024 -> dif, rest -> vT.
// ---------------------------------------------------------------------------
__global__ __launch_bounds__(256) void proj_gemm(const f16* __restrict__ A,
                                                 const f16* __restrict__ WqkT,
                                                 const f16* __restrict__ WvT,
                                                 const float* __restrict__ bq,
                                                 const float* __restrict__ bk,
                                                 const float* __restrict__ bv,
                                                 f16* __restrict__ dif,
                                                 f16* __restrict__ vT) {
    __shared__ f16 As[2][128 * 72];
    __shared__ f16 Bs[2][128 * 72];
    const int t = threadIdx.x;
    const int m0  = blockIdx.x * 128;
    const int n0g = blockIdx.y * 128;
    const bool isv = (n0g >= HID);
    const f16* BT = isv ? WvT : WqkT;
    const int n0 = n0g & (HID - 1);
    const int w = t >> 6, l = t & 63, quad = l >> 4, ln = l & 15;
    const int wm = (w >> 1) * 64, wn = (w & 1) * 64;
    const int srow = t >> 1, shalf = (t & 1) * 32;

    const f16* pa = A  + (size_t)(m0 + srow) * HID + shalf;
    const f16* pb = BT + (size_t)(n0 + srow) * HID + shalf;

    uint4 ar0 = *(const uint4*)(pa),      ar1 = *(const uint4*)(pa + 8);
    uint4 ar2 = *(const uint4*)(pa + 16), ar3 = *(const uint4*)(pa + 24);
    uint4 br0 = *(const uint4*)(pb),      br1 = *(const uint4*)(pb + 8);
    uint4 br2 = *(const uint4*)(pb + 16), br3 = *(const uint4*)(pb + 24);

    f32x4 acc[4][4] = {};
    int buf = 0;

    for (int k0 = 0; k0 < HID; k0 += 64) {
        f16* da = As[buf] + srow * 72 + shalf;
        f16* db = Bs[buf] + srow * 72 + shalf;
        *(uint4*)(da)      = ar0; *(uint4*)(da + 8)  = ar1;
        *(uint4*)(da + 16) = ar2; *(uint4*)(da + 24) = ar3;
        *(uint4*)(db)      = br0; *(uint4*)(db + 8)  = br1;
        *(uint4*)(db + 16) = br2; *(uint4*)(db + 24) = br3;
        __syncthreads();
        if (k0 + 64 < HID) {   // prefetch next slab while MFMAs run
            const f16* qa = pa + k0 + 64;
            const f16* qb = pb + k0 + 64;
            ar0 = *(const uint4*)(qa);      ar1 = *(const uint4*)(qa + 8);
            ar2 = *(const uint4*)(qa + 16); ar3 = *(const uint4*)(qa + 24);
            br0 = *(const uint4*)(qb);      br1 = *(const uint4*)(qb + 8);
            br2 = *(const uint4*)(qb + 16); br3 = *(const uint4*)(qb + 24);
        }
#pragma unroll
        for (int kh = 0; kh < 2; kh++) {
            f16x8 af[4], bf[4];
#pragma unroll
            for (int mt = 0; mt < 4; mt++)
                af[mt] = *(const f16x8*)(As[buf] + (wm + mt * 16 + ln) * 72 + kh * 32 + quad * 8);
#pragma unroll
            for (int nt = 0; nt < 4; nt++)
                bf[nt] = *(const f16x8*)(Bs[buf] + (wn + nt * 16 + ln) * 72 + kh * 32 + quad * 8);
#pragma unroll
            for (int mt = 0; mt < 4; mt++)
#pragma unroll
                for (int nt = 0; nt < 4; nt++)
                    acc[mt][nt] = __builtin_amdgcn_mfma_f32_16x16x32_f16(
                        af[mt], bf[nt], acc[mt][nt], 0, 0, 0);
        }
        buf ^= 1;
    }

#pragma unroll
    for (int mt = 0; mt < 4; mt++) {
#pragma unroll
        for (int nt = 0; nt < 4; nt++) {
            const int nl = n0 + wn + nt * 16 + ln;
            const int m_base = m0 + wm + mt * 16 + quad * 4;
            const int h = nl >> 6, e = nl & 63;
            if (!isv) {
                const float bb = bq[nl] - bk[nl];
#pragma unroll
                for (int r = 0; r < 4; r++) {
                    const int m = m_base + r;
                    const int b = m >> 11, s = m & 2047;
                    dif[((size_t)(b * 16 + h) * SEQ + s) * 64 + e] =
                        (f16)(acc[mt][nt][r] + bb);
                }
            } else {
                const float bb = bv[nl];
                const int b = m_base >> 11, s0 = m_base & 2047;
                f16 o[4];
#pragma unroll
                for (int r = 0; r < 4; r++) o[r] = (f16)(acc[mt][nt][r] + bb);
                *(ushort4*)(&vT[((size_t)(b * 16 + h) * 64 + e) * SEQ + s0]) =
                    *(ushort4*)o;
            }
        }
    }
}

// ---------------------------------------------------------------------------
// Output GEMM: out = (C0+C1) @ WoT^T * 65536 + bo. 128x64 tile, dbuf LDS.
// ---------------------------------------------------------------------------
__global__ __launch_bounds__(256) void out_gemm(const f16* __restrict__ C0,
                                                const f16* __restrict__ C1,
                                                const f16* __restrict__ WoT,
                                                const float* __restrict__ bo,
                                                float* __restrict__ out) {
    __shared__ f16 As[2][128 * 72];
    __shared__ f16 Bs[2][64 * 72];
    const int t = threadIdx.x;
    const int m0 = blockIdx.x * 128, n0 = blockIdx.y * 64;
    const int w = t >> 6, l = t & 63, quad = l >> 4, ln = l & 15;
    const int wm = (w >> 1) * 64, wn = (w & 1) * 32;
    const int arow = t >> 1, ahalf = (t & 1) * 32;
    const int brow = t >> 2, boff = (t & 3) * 16;

    const f16* pa0 = C0  + (size_t)(m0 + arow) * HID + ahalf;
    const f16* pa1 = C1  + (size_t)(m0 + arow) * HID + ahalf;
    const f16* pb  = WoT + (size_t)(n0 + brow) * HID + boff;

    f16x8 a0 = *(const f16x8*)(pa0)      + *(const f16x8*)(pa1);
    f16x8 a1 = *(const f16x8*)(pa0 + 8)  + *(const f16x8*)(pa1 + 8);
    f16x8 a2 = *(const f16x8*)(pa0 + 16) + *(const f16x8*)(pa1 + 16);
    f16x8 a3 = *(const f16x8*)(pa0 + 24) + *(const f16x8*)(pa1 + 24);
    uint4 b0 = *(const uint4*)(pb), b1 = *(const uint4*)(pb + 8);

    f32x4 acc[4][2] = {};
    int buf = 0;

    for (int k0 = 0; k0 < HID; k0 += 64) {
        f16* da = As[buf] + arow * 72 + ahalf;
        *(f16x8*)(da)      = a0; *(f16x8*)(da + 8)  = a1;
        *(f16x8*)(da + 16) = a2; *(f16x8*)(da + 24) = a3;
        f16* db = Bs[buf] + brow * 72 + boff;
        *(uint4*)(db) = b0; *(uint4*)(db + 8) = b1;
        __syncthreads();
        if (k0 + 64 < HID) {
            const int kn = k0 + 64;
            a0 = *(const f16x8*)(pa0 + kn)      + *(const f16x8*)(pa1 + kn);
            a1 = *(const f16x8*)(pa0 + kn + 8)  + *(const f16x8*)(pa1 + kn + 8);
            a2 = *(const f16x8*)(pa0 + kn + 16) + *(const f16x8*)(pa1 + kn + 16);
            a3 = *(const f16x8*)(pa0 + kn + 24) + *(const f16x8*)(pa1 + kn + 24);
            b0 = *(const uint4*)(pb + kn); b1 = *(const uint4*)(pb + kn + 8);
        }
#pragma unroll
        for (int kh = 0; kh < 2; kh++) {
            f16x8 af[4], bf[2];
#pragma unroll
            for (int mt = 0; mt < 4; mt++)
                af[mt] = *(const f16x8*)(As[buf] + (wm + mt * 16 + ln) * 72 + kh * 32 + quad * 8);
#pragma unroll
            for (int nt = 0; nt < 2; nt++)
                bf[nt] = *(const f16x8*)(Bs[buf] + (wn + nt * 16 + ln) * 72 + kh * 32 + quad * 8);
#pragma unroll
            for (int mt = 0; mt < 4; mt++)
#pragma unroll
                for (int nt = 0; nt < 2; nt++)
                    acc[mt][nt] = __builtin_amdgcn_mfma_f32_16x16x32_f16(
                        af[mt], bf[nt], acc[mt][nt], 0, 0, 0);
        }
        buf ^= 1;
    }

#pragma unroll
    for (int mt = 0; mt < 4; mt++)
#pragma unroll
        for (int nt = 0; nt < 2; nt++) {
            const int n = n0 + wn + nt * 16 + ln;
            const float bb = bo[n];
            const int m_base = m0 + wm + mt * 16 + quad * 4;
#pragma unroll
            for (int r = 0; r < 4; r++)
                out[(size_t)(m_base + r) * HID + n] =
                    acc[mt][nt][r] * 65536.0f + bb;
        }
}

// ---------------------------------------------------------------------------
// fp16 MFMA attention (R6 known-good): k-split x2, grid 16x32x2 = 1024 blocks.
// ---------------------------------------------------------------------------
__global__ __launch_bounds__(256) void attn_f16(const f16* __restrict__ dif,
                                                const f16* __restrict__ vT,
                                                f16* __restrict__ ctx0,
                                                f16* __restrict__ ctx1) {
    __shared__ f16 Qs[64 * 72];
    __shared__ f16 Ks[64 * 72];
    __shared__ f16 Vs[64 * 72];
    __shared__ f16 Ps[64 * 72];

    const int pq = blockIdx.x, bh = blockIdx.y, ks = blockIdx.z;
    f16* Cout = ks ? ctx1 : ctx0;
    const f16* D  = dif + (size_t)bh * SEQ * 64;
    const f16* VT = vT  + (size_t)bh * 64 * SEQ;
    const int b = bh >> 4, h = bh & 15;
    const int t = threadIdx.x, w = t >> 6, l = t & 63, quad = l >> 4, ln = l & 15;
    const int ve = t >> 2, vc = (t & 3) * 16;

    for (int half = 0; half < 2; half++) {
        const int qt = half ? (31 - pq) : pq;
        const int i0 = qt * 64;
        __syncthreads();

        // stage Q
#pragma unroll
        for (int rr = 0; rr < 2; rr++) {
            const int o = rr * 2048 + t * 8;
            uint4 v = *(const uint4*)(D + i0 * 64 + o);
            *(uint4*)(Qs + (o >> 6) * 72 + (o & 63)) = v;
        }

        f32x4 acc[4] = {};
        const int kt0 = qt + ks;

        uint4 kr0, kr1, vr0, vr1;
        if (kt0 < 32) {
            const int j0 = kt0 * 64;
            kr0 = *(const uint4*)(D + j0 * 64 + t * 8);
            kr1 = *(const uint4*)(D + j0 * 64 + 2048 + t * 8);
            vr0 = *(const uint4*)(VT + (size_t)ve * SEQ + j0 + vc);
            vr1 = *(const uint4*)(VT + (size_t)ve * SEQ + j0 + vc + 8);
        }

        for (int kt = kt0; kt < 32; kt += 2) {
            __syncthreads();

            {
                const int o0 = t * 8, o1 = 2048 + t * 8;
                *(uint4*)(Ks + (o0 >> 6) * 72 + (o0 & 63)) = kr0;
                *(uint4*)(Ks + (o1 >> 6) * 72 + (o1 & 63)) = kr1;
                *(uint4*)(Vs + ve * 72 + vc)     = vr0;
                *(uint4*)(Vs + ve * 72 + vc + 8) = vr1;
            }
            __syncthreads();

            if (kt + 2 < 32) {
                const int j2 = (kt + 2) * 64;
                kr0 = *(const uint4*)(D + j2 * 64 + t * 8);
                kr1 = *(const uint4*)(D + j2 * 64 + 2048 + t * 8);
                vr0 = *(const uint4*)(VT + (size_t)ve * SEQ + j2 + vc);
                vr1 = *(const uint4*)(VT + (size_t)ve * SEQ + j2 + vc + 8);
            }

            // S = Q . K^T
            f32x4 s[4] = {};
#pragma unroll
            for (int kh = 0; kh < 2; kh++) {
                f16x8 a = *(const f16x8*)(Qs + (w * 16 + ln) * 72 + kh * 32 + quad * 8);
#pragma unroll
                for (int nt = 0; nt < 4; nt++) {
                    f16x8 bfr = *(const f16x8*)(Ks + (nt * 16 + ln) * 72 + kh * 32 + quad * 8);
                    s[nt] = __builtin_amdgcn_mfma_f32_16x16x32_f16(a, bfr, s[nt], 0, 0, 0);
                }
            }

            // P = mask * exp(-0.5*s) * 2^-16
            const bool full = (kt > qt);
#pragma unroll
            for (int nt = 0; nt < 4; nt++)
#pragma unroll
                for (int r = 0; r < 4; r++) {
                    const int iloc = w * 16 + quad * 4 + r;
                    const int jloc = nt * 16 + ln;
                    float p = (full || (jloc > iloc))
                                  ? fminf(__expf(-0.5f * s[nt][r]) * 0x1p-16f, 60000.0f)
                                  : 0.0f;
                    Ps[iloc * 72 + jloc] = (f16)p;
                }

            // ctx += P @ V
#pragma unroll
            for (int kh = 0; kh < 2; kh++) {
                f16x8 a = *(const f16x8*)(Ps + (w * 16 + ln) * 72 + kh * 32 + quad * 8);
#pragma unroll
                for (int nt = 0; nt < 4; nt++) {
                    f16x8 bfr = *(const f16x8*)(Vs + (nt * 16 + ln) * 72 + kh * 32 + quad * 8);
                    acc[nt] = __builtin_amdgcn_mfma_f32_16x16x32_f16(a, bfr, acc[nt], 0, 0, 0);
                }
            }
        }

#pragma unroll
        for (int nt = 0; nt < 4; nt++)
#pragma unroll
            for (int r = 0; r < 4; r++) {
                const int iloc = w * 16 + quad * 4 + r;
                Cout[(size_t)(b * SEQ + i0 + iloc) * HID + h * 64 + nt * 16 + ln] =
                    (f16)acc[nt][r];
            }
    }
}

// ---------------------------------------------------------------------------
extern "C" void kernel_launch(void* const* d_in, const int* in_sizes, int n_in,
                              void* d_out, int out_size, void* d_ws, size_t ws_size,
                              hipStream_t stream) {
    const float* x  = (const float*)d_in[0];
    const float* Wq = (const float*)d_in[1];
    const float* bq = (const float*)d_in[2];
    const float* Wk = (const float*)d_in[3];
    const float* bk = (const float*)d_in[4];
    const float* Wv = (const float*)d_in[5];
    const float* bv = (const float*)d_in[6];
    const float* Wo = (const float*)d_in[7];
    const float* bo = (const float*)d_in[8];
    float* out = (float*)d_out;

    char* ws = (char*)d_ws;
    f16* xh   = (f16*)(ws);               // 8 MB  [M][1024]
    f16* WqkT = (f16*)(ws + (8 << 20));   // 2 MB  [n][k]
    f16* WvT  = (f16*)(ws + (10 << 20));  // 2 MB
    f16* WoT  = (f16*)(ws + (12 << 20));  // 2 MB
    f16* dif  = (f16*)(ws + (14 << 20));  // 8 MB  [bh][s][64]
    f16* vT   = (f16*)(ws + (22 << 20));  // 8 MB  [bh][e][s]
    f16* ctx0 = (f16*)(ws + (30 << 20));  // 8 MB  partial (x 2^-16)
    f16* ctx1 = (f16*)(ws + (38 << 20));  // 8 MB  partial

    prep<<<dim3(16, 16, 4), 256, 0, stream>>>(x, Wq, Wk, Wv, Wo,
                                              xh, WqkT, WvT, WoT);
    proj_gemm<<<dim3(MTOT / 128, 16), 256, 0, stream>>>(xh, WqkT, WvT,
                                                        bq, bk, bv, dif, vT);
    attn_f16<<<dim3(16, BH, 2), 256, 0, stream>>>(dif, vT, ctx0, ctx1);
    out_gemm<<<dim3(MTOT / 128, 16), 256, 0, stream>>>(ctx0, ctx1, WoT, bo, out);
}